// Round 1
// 336.660 us; speedup vs baseline: 1.0164x; 1.0164x over previous
//
#include <hip/hip_runtime.h>

// Shapes (fixed by the reference): x (2,64,256,256), out (2,256,256,256)
#define EPSV 1e-5f

typedef short bf16x8 __attribute__((ext_vector_type(8)));
typedef float f32x4  __attribute__((ext_vector_type(4)));

__device__ __forceinline__ unsigned int f32_bf16(float f) {
    unsigned int u = __float_as_uint(f);
    u += 0x7fff + ((u >> 16) & 1);           // RNE
    return u >> 16;
}
__device__ __forceinline__ float bf16_f32(unsigned short s) {
    return __uint_as_float(((unsigned int)s) << 16);
}

// async global->LDS, 16B per lane; LDS dest = wave-uniform base + lane*16
__device__ __forceinline__ void gload_lds16(const unsigned short* g, unsigned short* l) {
    __builtin_amdgcn_global_load_lds(
        (const __attribute__((address_space(1))) unsigned int*)g,
        (__attribute__((address_space(3))) unsigned int*)l, 16, 0, 0);
}

// C intermediate: 4 h-planes (64 h each), rows = (i*256+j) for ONE b at a time.
#define CPL ((size_t)65536 * 64)   // elements per plane

// ---------------------------------------------------------------------------
// K0: LayerNorm -> bf16 xn. 8 rows/block, 32 lanes per row, register-resident.
// ---------------------------------------------------------------------------
__global__ __launch_bounds__(256) void k_ln(
    const float* __restrict__ x, const float* __restrict__ ln_w,
    const float* __restrict__ ln_b, unsigned short* __restrict__ xn)
{
    const int tid = threadIdx.x;
    const size_t row = (size_t)blockIdx.x * 8 + (tid >> 5);
    const int c0 = (tid & 31) * 8;

    const float* src = x + row * 256 + c0;
    const float4 a0 = *reinterpret_cast<const float4*>(src);
    const float4 a1 = *reinterpret_cast<const float4*>(src + 4);
    float v[8] = {a0.x, a0.y, a0.z, a0.w, a1.x, a1.y, a1.z, a1.w};

    float s1 = 0.f, s2 = 0.f;
#pragma unroll
    for (int k = 0; k < 8; ++k) { s1 += v[k]; s2 += v[k] * v[k]; }
#pragma unroll
    for (int m = 16; m > 0; m >>= 1) {
        s1 += __shfl_xor(s1, m, 32);
        s2 += __shfl_xor(s2, m, 32);
    }
    const float mu = s1 * (1.f / 256.f);
    const float rs = rsqrtf(s2 * (1.f / 256.f) - mu * mu + EPSV);

    const float4 w0 = *reinterpret_cast<const float4*>(ln_w + c0);
    const float4 w1 = *reinterpret_cast<const float4*>(ln_w + c0 + 4);
    const float4 b0 = *reinterpret_cast<const float4*>(ln_b + c0);
    const float4 b1 = *reinterpret_cast<const float4*>(ln_b + c0 + 4);
    const float wv[8] = {w0.x, w0.y, w0.z, w0.w, w1.x, w1.y, w1.z, w1.w};
    const float bv[8] = {b0.x, b0.y, b0.z, b0.w, b1.x, b1.y, b1.z, b1.w};

    uint4 p;
    unsigned int y[8];
#pragma unroll
    for (int k = 0; k < 8; ++k)
        y[k] = f32_bf16((v[k] - mu) * rs * wv[k] + bv[k]);
    p.x = y[0] | (y[1] << 16);
    p.y = y[2] | (y[3] << 16);
    p.z = y[4] | (y[5] << 16);
    p.w = y[6] | (y[7] << 16);
    *reinterpret_cast<uint4*>(xn + row * 256 + c0) = p;
}

// ---------------------------------------------------------------------------
// Kcnt: scale[b,i,j] = 1 / (64 * (sum_m mask[b,m,i]*mask[b,m,j] + EPS))
// ---------------------------------------------------------------------------
__global__ __launch_bounds__(256) void k_cnt(const int* __restrict__ mask,
                                             float* __restrict__ scale)
{
    const int b = blockIdx.y, i = blockIdx.x, j = threadIdx.x;
    float c = 0.f;
    for (int m = 0; m < 64; ++m) {
        int mi = mask[(b * 64 + m) * 256 + i];
        int mj = mask[(b * 64 + m) * 256 + j];
        c += (mi && mj) ? 1.f : 0.f;
    }
    scale[(b * 256 + i) * 256 + j] = 1.f / (64.f * (c + EPSV));
}

// ---------------------------------------------------------------------------
// Kpack_wlr: pack Wl (nt 0..15) and Wr (nt 16..31) into MFMA B-fragment order.
// ---------------------------------------------------------------------------
__global__ __launch_bounds__(256) void k_pack_wlr(
    const float* __restrict__ Wl, const float* __restrict__ Wr,
    unsigned short* __restrict__ Wp2)
{
    const int t = blockIdx.x * 256 + threadIdx.x;   // 0..16383
    const int lane = t & 63, nt = (t >> 6) & 31, kb = t >> 11;
    const int quad = lane >> 4;
    const float* W = (nt < 16) ? Wl : Wr;
    const int n = (nt & 15) * 16 + (lane & 15);
    const int k0 = kb * 32 + quad * 8;
    unsigned int p[4];
#pragma unroll
    for (int pp = 0; pp < 4; ++pp) {
        unsigned int lo = f32_bf16(W[(k0 + 2 * pp) * 256 + n]);
        unsigned int hi = f32_bf16(W[(k0 + 2 * pp + 1) * 256 + n]);
        p[pp] = lo | (hi << 16);
    }
    unsigned int* dst = (unsigned int*)Wp2 + t * 4;
#pragma unroll
    for (int pp = 0; pp < 4; ++pp) dst[pp] = p[pp];
}

// ---------------------------------------------------------------------------
// Kpack_wo: same packing for Wo (N=256, nt 0..15).
// ---------------------------------------------------------------------------
__global__ __launch_bounds__(256) void k_pack_wo(
    const float* __restrict__ Wo, unsigned short* __restrict__ Wp)
{
    const int t = blockIdx.x * 256 + threadIdx.x;   // 0..8191
    const int lane = t & 63, nt = (t >> 6) & 15, kb = t >> 10;
    const int quad = lane >> 4;
    const int n = nt * 16 + (lane & 15);
    const int k0 = kb * 32 + quad * 8;
    unsigned int p[4];
#pragma unroll
    for (int pp = 0; pp < 4; ++pp) {
        unsigned int lo = f32_bf16(Wo[(k0 + 2 * pp) * 256 + n]);
        unsigned int hi = f32_bf16(Wo[(k0 + 2 * pp + 1) * 256 + n]);
        p[pp] = lo | (hi << 16);
    }
    unsigned int* dst = (unsigned int*)Wp + t * 4;
#pragma unroll
    for (int pp = 0; pp < 4; ++pp) dst[pp] = p[pp];
}

// ---------------------------------------------------------------------------
// K1: projection GEMM. Block = (b, i): A-rows are the 64 m's of one (b,i).
// Epilogue stores bf16 L/R TRANSPOSED as Lt[b][i][h][m] (m-minor, 128B lines):
// lane's 4 acc rows are 4 consecutive m -> single uint2 store per nt.
// ---------------------------------------------------------------------------
__global__ __launch_bounds__(256) void k_proj_mfma(
    const unsigned short* __restrict__ xn, const int* __restrict__ mask,
    const unsigned short* __restrict__ Wp2,
    const float* __restrict__ bl, const float* __restrict__ br,
    unsigned short* __restrict__ Lt, unsigned short* __restrict__ Rt)
{
    __shared__ __align__(16) unsigned short ash[64 * 264];   // 33792 B
    __shared__ float4 bsh[2048];                             // 32768 B
    const int tid = threadIdx.x;
    const int lane = tid & 63, wave = tid >> 6;
    const int quad = lane >> 4, mrow = lane & 15;
    const int b = blockIdx.x >> 8, i = blockIdx.x & 255;

    // Stage A: 64 m-rows (xn rows (b,m,i)), coalesced uint4 copies.
#pragma unroll
    for (int it = 0; it < 8; ++it) {
        const int c = tid + it * 256;
        const int row = c >> 5, col = (c & 31) * 8;
        *reinterpret_cast<uint4*>(&ash[row * 264 + col]) =
            *reinterpret_cast<const uint4*>(
                xn + ((size_t)((b * 64 + row) * 256 + i)) * 256 + col);
    }

    f32x4 acc[32];
#pragma unroll
    for (int nt = 0; nt < 32; ++nt) acc[nt] = {0.f, 0.f, 0.f, 0.f};

    const float4* wpv = reinterpret_cast<const float4*>(Wp2);
    const int arow = wave * 16 + mrow;

    for (int kb = 0; kb < 8; ++kb) {
        if (kb) __syncthreads();
#pragma unroll
        for (int it = 0; it < 8; ++it)
            bsh[tid + it * 256] = wpv[kb * 2048 + tid + it * 256];
        __syncthreads();

        const bf16x8 afr = *reinterpret_cast<const bf16x8*>(
            &ash[arow * 264 + kb * 32 + quad * 8]);
        const bf16x8* bptr = reinterpret_cast<const bf16x8*>(bsh);
#pragma unroll
        for (int nt = 0; nt < 32; ++nt) {
            bf16x8 bfr = bptr[nt * 64 + lane];
            acc[nt] = __builtin_amdgcn_mfma_f32_16x16x32_bf16(afr, bfr, acc[nt], 0, 0, 0);
        }
    }

    // Epilogue: m = wave*16 + quad*4 + r; col = h. Store 4 consecutive m (8B).
    const int m0 = wave * 16 + quad * 4;
    float mf[4];
#pragma unroll
    for (int r = 0; r < 4; ++r)
        mf[r] = mask[(b * 64 + m0 + r) * 256 + i] ? 1.f : 0.f;

#pragma unroll
    for (int nt = 0; nt < 32; ++nt) {
        const int col = (nt & 15) * 16 + mrow;
        const float bias = (nt < 16) ? bl[col] : br[col];
        unsigned short* T = (nt < 16) ? Lt : Rt;
        uint2 p;
        p.x = f32_bf16((acc[nt][0] + bias) * mf[0]) |
              (f32_bf16((acc[nt][1] + bias) * mf[1]) << 16);
        p.y = f32_bf16((acc[nt][2] + bias) * mf[2]) |
              (f32_bf16((acc[nt][3] + bias) * mf[3]) << 16);
        *reinterpret_cast<uint2*>(
            T + ((size_t)((b * 256 + i) * 256 + col)) * 64 + m0) = p;
    }
}

// ---------------------------------------------------------------------------
// K2: C[i,j,h] = scale[b,i,j] * sum_m Lt[b,i,h,m]*Rt[b,j,h,m] via bf16 MFMA
// (K = m). Block = 32i x 16j x 64h (one b, one h-plane quarter). 4 waves:
// wave = (i-subtile, h-half). LDS [row][hs][64m] staged by global_load_lds
// with XOR-pre-swizzled source (16B blocks ^ row&7) so ds_read_b128 frags
// are conflict-light. Output bf16, h-contiguous uint2 per lane per iter.
// ---------------------------------------------------------------------------
__global__ __launch_bounds__(256) void k_outer_mfma(
    const unsigned short* __restrict__ Lt, const unsigned short* __restrict__ Rt,
    const float* __restrict__ scale, unsigned short* __restrict__ C, int b)
{
    __shared__ __align__(16) unsigned short ash[32 * 512];   // 32 KB [i][hs][m]
    __shared__ __align__(16) unsigned short bsh[16 * 512];   // 16 KB [j][hs][m]
    const int tid = threadIdx.x;
    const int lane = tid & 63, w = tid >> 6;
    const int quad = lane >> 4, l15 = lane & 15;
    const int jt0 = blockIdx.x * 16, it0 = blockIdx.y * 32;
    const int hc = blockIdx.z;
    const int h0 = hc * 64;

    const int wit = (w >> 1) * 16;   // wave's i sub-tile base (0 or 16)
    const int hh0 = (w & 1) * 4;     // wave's hs half (0..3 or 4..7)
    const int ci = wit + quad * 4;   // lane's local i row base

    float scl[4];
#pragma unroll
    for (int r = 0; r < 4; ++r)
        scl[r] = scale[((size_t)(b * 256 + it0 + ci + r)) * 256 + jt0 + l15];

    const int hs_l = lane >> 3, mb_l = lane & 7;
    const int ai = wit + l15;
    const int sa0 = ai * 512 + ((quad ^ (ai & 7)) * 8);
    const int sa1 = ai * 512 + (((4 | quad) ^ (ai & 7)) * 8);
    const int sb0 = l15 * 512 + ((quad ^ (l15 & 7)) * 8);
    const int sb1 = l15 * 512 + (((4 | quad) ^ (l15 & 7)) * 8);

    unsigned short* Cbase = C + (size_t)hc * CPL +
        ((size_t)(it0 + ci) * 256 + jt0 + l15) * 64;

    for (int iter = 0; iter < 8; ++iter) {
        if (iter) __syncthreads();          // prev iter's LDS reads done
        const int hb = h0 + iter * 8;
        // stage: wave w loads 8 A-rows + 4 B-rows (1KB each, contiguous src)
#pragma unroll
        for (int k = 0; k < 8; ++k) {
            const int li = w * 8 + k;
            gload_lds16(
                Lt + ((size_t)(b * 256 + it0 + li) * 256 + hb + hs_l) * 64 +
                     ((mb_l ^ (li & 7)) * 8),
                &ash[li * 512]);
        }
#pragma unroll
        for (int k = 0; k < 4; ++k) {
            const int lj = w * 4 + k;
            gload_lds16(
                Rt + ((size_t)(b * 256 + jt0 + lj) * 256 + hb + hs_l) * 64 +
                     ((mb_l ^ (lj & 7)) * 8),
                &bsh[lj * 512]);
        }
        __syncthreads();                    // drains vmcnt (gl_lds done)

        f32x4 acch[4];
#pragma unroll
        for (int q = 0; q < 4; ++q) acch[q] = {0.f, 0.f, 0.f, 0.f};
#pragma unroll
        for (int q = 0; q < 4; ++q) {
            const int hs = hh0 + q;
            const bf16x8 a0 = *reinterpret_cast<const bf16x8*>(&ash[sa0 + hs * 64]);
            const bf16x8 a1 = *reinterpret_cast<const bf16x8*>(&ash[sa1 + hs * 64]);
            const bf16x8 b0 = *reinterpret_cast<const bf16x8*>(&bsh[sb0 + hs * 64]);
            const bf16x8 b1 = *reinterpret_cast<const bf16x8*>(&bsh[sb1 + hs * 64]);
            acch[q] = __builtin_amdgcn_mfma_f32_16x16x32_bf16(a0, b0, acch[q], 0, 0, 0);
            acch[q] = __builtin_amdgcn_mfma_f32_16x16x32_bf16(a1, b1, acch[q], 0, 0, 0);
        }
        // store: per r, 4 contiguous h as bf16 (uint2). L2 merges the 128B line.
#pragma unroll
        for (int r = 0; r < 4; ++r) {
            const float s = scl[r];
            uint2 p;
            p.x = f32_bf16(acch[0][r] * s) | (f32_bf16(acch[1][r] * s) << 16);
            p.y = f32_bf16(acch[2][r] * s) | (f32_bf16(acch[3][r] * s) << 16);
            *reinterpret_cast<uint2*>(Cbase + (size_t)r * 16384 + iter * 8 + hh0) = p;
        }
    }
}

// ---------------------------------------------------------------------------
// K3: rows GEMM: out_row = bf16C_row @ bf16(Wo) + bo. A staged from the 4
// bf16 h-planes (plain uint4 copies, no conversion).
// ---------------------------------------------------------------------------
__global__ __launch_bounds__(256) void k_wo_mfma(
    float* __restrict__ io, const unsigned short* __restrict__ C,
    const unsigned short* __restrict__ Wp, const float* __restrict__ bo)
{
    __shared__ __align__(16) unsigned short ash[64 * 264];   // 33792 B
    __shared__ float4 bsh[1024];                             // 16384 B
    const int tid = threadIdx.x;
    const int lane = tid & 63, wave = tid >> 6;
    const int quad = lane >> 4, mrow = lane & 15;
    const size_t r0 = (size_t)blockIdx.x * 64;

    // Stage A: 64 rows x 256 bf16 from 4 planes (128B per plane per row).
#pragma unroll
    for (int it = 0; it < 8; ++it) {
        const int c = tid + it * 256;
        const int row = c >> 5, chunk = c & 31;
        *reinterpret_cast<uint4*>(&ash[row * 264 + chunk * 8]) =
            *reinterpret_cast<const uint4*>(
                C + (size_t)(chunk >> 3) * CPL + (r0 + row) * 64 + (chunk & 7) * 8);
    }

    f32x4 acc[16];
#pragma unroll
    for (int nt = 0; nt < 16; ++nt) acc[nt] = {0.f, 0.f, 0.f, 0.f};

    const float4* wpv = reinterpret_cast<const float4*>(Wp);
    const int arow = wave * 16 + mrow;

    for (int kb = 0; kb < 8; ++kb) {
        if (kb) __syncthreads();
#pragma unroll
        for (int it = 0; it < 4; ++it)
            bsh[tid + it * 256] = wpv[kb * 1024 + tid + it * 256];
        __syncthreads();

        const bf16x8 afr = *reinterpret_cast<const bf16x8*>(
            &ash[arow * 264 + kb * 32 + quad * 8]);
        const bf16x8* bptr = reinterpret_cast<const bf16x8*>(bsh);
#pragma unroll
        for (int nt = 0; nt < 16; ++nt) {
            bf16x8 bfr = bptr[nt * 64 + lane];
            acc[nt] = __builtin_amdgcn_mfma_f32_16x16x32_bf16(afr, bfr, acc[nt], 0, 0, 0);
        }
    }

#pragma unroll
    for (int nt = 0; nt < 16; ++nt) {
        const int col = nt * 16 + mrow;
        const float bov = bo[col];
#pragma unroll
        for (int r = 0; r < 4; ++r)
            io[(r0 + wave * 16 + quad * 4 + r) * 256 + col] = acc[nt][r] + bov;
    }
}

// ---------------------------------------------------------------------------
extern "C" void kernel_launch(void* const* d_in, const int* in_sizes, int n_in,
                              void* d_out, int out_size, void* d_ws, size_t ws_size,
                              hipStream_t stream)
{
    const float* x    = (const float*)d_in[0];
    const int*   mask = (const int*)  d_in[1];
    const float* ln_w = (const float*)d_in[2];
    const float* ln_b = (const float*)d_in[3];
    const float* Wl   = (const float*)d_in[4];
    const float* bl   = (const float*)d_in[5];
    const float* Wr   = (const float*)d_in[6];
    const float* br   = (const float*)d_in[7];
    const float* Wo   = (const float*)d_in[8];
    const float* bo   = (const float*)d_in[9];

    float* out = (float*)d_out;
    char*  ws  = (char*)d_ws;
    unsigned short* Lt    = (unsigned short*)(ws);                 // 16 MiB [b][i][h][m]
    unsigned short* Rt    = (unsigned short*)(ws + 16777216);      // 16 MiB [b][j][h][m]
    float*          scale = (float*)         (ws + 33554432);      // 512 KiB
    unsigned short* Wp    = (unsigned short*)(ws + 34078720);      // 128 KiB (Wo)
    unsigned short* Wp2   = (unsigned short*)(ws + 34209792);      // 256 KiB (Wl|Wr)
    unsigned short* xn    = (unsigned short*)(ws + 34471936);      // 16 MiB (dead after k_proj)
    unsigned short* C     = (unsigned short*)(ws + 34471936);      // 32 MiB, aliases xn, reused per b

    k_ln<<<4096, 256, 0, stream>>>(x, ln_w, ln_b, xn);
    k_pack_wlr<<<64, 256, 0, stream>>>(Wl, Wr, Wp2);
    k_pack_wo<<<32, 256, 0, stream>>>(Wo, Wp);
    k_cnt<<<dim3(256, 2), 256, 0, stream>>>(mask, scale);
    k_proj_mfma<<<512, 256, 0, stream>>>(xn, mask, Wp2, bl, br, Lt, Rt);
    for (int b = 0; b < 2; ++b) {
        k_outer_mfma<<<dim3(16, 8, 4), 256, 0, stream>>>(Lt, Rt, scale, C, b);
        k_wo_mfma<<<1024, 256, 0, stream>>>(out + (size_t)b * 65536 * 256, C, Wp, bo);
    }
}

// Round 2
// 305.239 us; speedup vs baseline: 1.1210x; 1.1029x over previous
//
#include <hip/hip_runtime.h>

// Shapes (fixed by the reference): x (2,64,256,256), out (2,256,256,256)
#define EPSV 1e-5f

typedef short bf16x8 __attribute__((ext_vector_type(8)));
typedef float f32x4  __attribute__((ext_vector_type(4)));

__device__ __forceinline__ unsigned int f32_bf16(float f) {
    unsigned int u = __float_as_uint(f);
    u += 0x7fff + ((u >> 16) & 1);           // RNE
    return u >> 16;
}

// async global->LDS, 16B per lane; LDS dest = wave-uniform base + lane*16
__device__ __forceinline__ void gload_lds16(const unsigned short* g, unsigned short* l) {
    __builtin_amdgcn_global_load_lds(
        (const __attribute__((address_space(1))) unsigned int*)g,
        (__attribute__((address_space(3))) unsigned int*)l, 16, 0, 0);
}

// C intermediate: 4 h-planes (64 h each), rows = (i*256+j) for ONE b at a time.
#define CPL ((size_t)65536 * 64)   // elements per plane

// ---------------------------------------------------------------------------
// K_setup: one launch for Wl/Wr pack (blocks 0..63), Wo pack (64..95),
// and the pair-count scale (96..607).
// ---------------------------------------------------------------------------
__global__ __launch_bounds__(256) void k_setup(
    const float* __restrict__ Wl, const float* __restrict__ Wr,
    const float* __restrict__ Wo, const int* __restrict__ mask,
    unsigned short* __restrict__ Wp2, unsigned short* __restrict__ Wp,
    float* __restrict__ scale)
{
    const int bid = blockIdx.x;
    if (bid < 64) {
        // pack Wl (nt 0..15) and Wr (nt 16..31) into MFMA B-fragment order
        const int t = bid * 256 + threadIdx.x;   // 0..16383
        const int lane = t & 63, nt = (t >> 6) & 31, kb = t >> 11;
        const int quad = lane >> 4;
        const float* W = (nt < 16) ? Wl : Wr;
        const int n = (nt & 15) * 16 + (lane & 15);
        const int k0 = kb * 32 + quad * 8;
        unsigned int p[4];
#pragma unroll
        for (int pp = 0; pp < 4; ++pp) {
            unsigned int lo = f32_bf16(W[(k0 + 2 * pp) * 256 + n]);
            unsigned int hi = f32_bf16(W[(k0 + 2 * pp + 1) * 256 + n]);
            p[pp] = lo | (hi << 16);
        }
        unsigned int* dst = (unsigned int*)Wp2 + t * 4;
#pragma unroll
        for (int pp = 0; pp < 4; ++pp) dst[pp] = p[pp];
    } else if (bid < 96) {
        // pack Wo (N=256, nt 0..15)
        const int t = (bid - 64) * 256 + threadIdx.x;   // 0..8191
        const int lane = t & 63, nt = (t >> 6) & 15, kb = t >> 10;
        const int quad = lane >> 4;
        const int n = nt * 16 + (lane & 15);
        const int k0 = kb * 32 + quad * 8;
        unsigned int p[4];
#pragma unroll
        for (int pp = 0; pp < 4; ++pp) {
            unsigned int lo = f32_bf16(Wo[(k0 + 2 * pp) * 256 + n]);
            unsigned int hi = f32_bf16(Wo[(k0 + 2 * pp + 1) * 256 + n]);
            p[pp] = lo | (hi << 16);
        }
        unsigned int* dst = (unsigned int*)Wp + t * 4;
#pragma unroll
        for (int pp = 0; pp < 4; ++pp) dst[pp] = p[pp];
    } else {
        // scale[b,i,j] = 1 / (64 * (sum_m mask[b,m,i]*mask[b,m,j] + EPS))
        const int idx = bid - 96;              // 0..511
        const int b = idx >> 8, i = idx & 255, j = threadIdx.x;
        float c = 0.f;
        for (int m = 0; m < 64; ++m) {
            int mi = mask[(b * 64 + m) * 256 + i];
            int mj = mask[(b * 64 + m) * 256 + j];
            c += (mi && mj) ? 1.f : 0.f;
        }
        scale[(b * 256 + i) * 256 + j] = 1.f / (64.f * (c + EPSV));
    }
}

// ---------------------------------------------------------------------------
// K1: fused LayerNorm + projection GEMM. Block = (b, i): the 64 m-rows of
// x[b, :, i, :] are LayerNorm'ed in-register (each row used by exactly this
// block) and written bf16 straight into the A-tile in LDS. Then
// [64 m x 256 d] @ [Wl|Wr] + bias, * row-mask, stored TRANSPOSED as
// Lt[b][i][h][m] (m-minor 128B lines) for the outer-product stage.
// ---------------------------------------------------------------------------
__global__ __launch_bounds__(256) void k_projln(
    const float* __restrict__ x, const int* __restrict__ mask,
    const unsigned short* __restrict__ Wp2,
    const float* __restrict__ ln_w, const float* __restrict__ ln_b,
    const float* __restrict__ bl, const float* __restrict__ br,
    unsigned short* __restrict__ Lt, unsigned short* __restrict__ Rt)
{
    __shared__ __align__(16) unsigned short ash[64 * 264];   // 33792 B
    __shared__ float4 bsh[2048];                             // 32768 B
    const int tid = threadIdx.x;
    const int lane = tid & 63, wave = tid >> 6;
    const int quad = lane >> 4, mrow = lane & 15;
    const int b = blockIdx.x >> 8, i = blockIdx.x & 255;

    // --- LayerNorm 64 rows: 8 passes, 8 rows/pass, 32 lanes per row ---
    const int lrow = tid >> 5;            // 0..7
    const int c0 = (tid & 31) * 8;
    const float4 w0 = *reinterpret_cast<const float4*>(ln_w + c0);
    const float4 w1 = *reinterpret_cast<const float4*>(ln_w + c0 + 4);
    const float4 g0 = *reinterpret_cast<const float4*>(ln_b + c0);
    const float4 g1 = *reinterpret_cast<const float4*>(ln_b + c0 + 4);
    const float wv[8] = {w0.x, w0.y, w0.z, w0.w, w1.x, w1.y, w1.z, w1.w};
    const float gv[8] = {g0.x, g0.y, g0.z, g0.w, g1.x, g1.y, g1.z, g1.w};

#pragma unroll
    for (int p = 0; p < 8; ++p) {
        const int m = p * 8 + lrow;
        const float* src = x + ((size_t)((b * 64 + m) * 256 + i)) * 256 + c0;
        const float4 a0 = *reinterpret_cast<const float4*>(src);
        const float4 a1 = *reinterpret_cast<const float4*>(src + 4);
        float v[8] = {a0.x, a0.y, a0.z, a0.w, a1.x, a1.y, a1.z, a1.w};
        float s1 = 0.f, s2 = 0.f;
#pragma unroll
        for (int k = 0; k < 8; ++k) { s1 += v[k]; s2 += v[k] * v[k]; }
#pragma unroll
        for (int sh = 16; sh > 0; sh >>= 1) {
            s1 += __shfl_xor(s1, sh, 32);
            s2 += __shfl_xor(s2, sh, 32);
        }
        const float mu = s1 * (1.f / 256.f);
        const float rs = rsqrtf(s2 * (1.f / 256.f) - mu * mu + EPSV);
        unsigned int y[8];
#pragma unroll
        for (int k = 0; k < 8; ++k)
            y[k] = f32_bf16((v[k] - mu) * rs * wv[k] + gv[k]);
        uint4 pk;
        pk.x = y[0] | (y[1] << 16);
        pk.y = y[2] | (y[3] << 16);
        pk.z = y[4] | (y[5] << 16);
        pk.w = y[6] | (y[7] << 16);
        *reinterpret_cast<uint4*>(&ash[m * 264 + c0]) = pk;
    }

    f32x4 acc[32];
#pragma unroll
    for (int nt = 0; nt < 32; ++nt) acc[nt] = {0.f, 0.f, 0.f, 0.f};

    const float4* wpv = reinterpret_cast<const float4*>(Wp2);
    const int arow = wave * 16 + mrow;

    for (int kb = 0; kb < 8; ++kb) {
        if (kb) __syncthreads();
#pragma unroll
        for (int it = 0; it < 8; ++it)
            bsh[tid + it * 256] = wpv[kb * 2048 + tid + it * 256];
        __syncthreads();    // (kb==0: also covers the ash writes above)

        const bf16x8 afr = *reinterpret_cast<const bf16x8*>(
            &ash[arow * 264 + kb * 32 + quad * 8]);
        const bf16x8* bptr = reinterpret_cast<const bf16x8*>(bsh);
#pragma unroll
        for (int nt = 0; nt < 32; ++nt) {
            bf16x8 bfr = bptr[nt * 64 + lane];
            acc[nt] = __builtin_amdgcn_mfma_f32_16x16x32_bf16(afr, bfr, acc[nt], 0, 0, 0);
        }
    }

    // Epilogue: m = wave*16 + quad*4 + r; col = h. Store 4 consecutive m (8B).
    const int m0 = wave * 16 + quad * 4;
    float mf[4];
#pragma unroll
    for (int r = 0; r < 4; ++r)
        mf[r] = mask[(b * 64 + m0 + r) * 256 + i] ? 1.f : 0.f;

#pragma unroll
    for (int nt = 0; nt < 32; ++nt) {
        const int col = (nt & 15) * 16 + mrow;
        const float bias = (nt < 16) ? bl[col] : br[col];
        unsigned short* T = (nt < 16) ? Lt : Rt;
        uint2 p;
        p.x = f32_bf16((acc[nt][0] + bias) * mf[0]) |
              (f32_bf16((acc[nt][1] + bias) * mf[1]) << 16);
        p.y = f32_bf16((acc[nt][2] + bias) * mf[2]) |
              (f32_bf16((acc[nt][3] + bias) * mf[3]) << 16);
        *reinterpret_cast<uint2*>(
            T + ((size_t)((b * 256 + i) * 256 + col)) * 64 + m0) = p;
    }
}

// ---------------------------------------------------------------------------
// K2: C[i,j,h] = scale[b,i,j] * sum_m Lt[b,i,h,m]*Rt[b,j,h,m] via bf16 MFMA
// (K = m). Tile 32i x 16j x 64h. Packed-bf16 C pieces accumulate in REGISTERS
// (pc[8][4], static indexing) and are stored once after the loop, so the
// per-iter vmcnt(0)+barrier drains only the 12 global_load_lds.
// Grid is XCD-swizzled (512 = 8 x 64): each XCD owns 4 i-tiles x 16 j-tiles
// of one hc (~3 MB working set -> L2-resident).
// ---------------------------------------------------------------------------
__global__ __launch_bounds__(256) void k_outer_mfma(
    const unsigned short* __restrict__ Lt, const unsigned short* __restrict__ Rt,
    const float* __restrict__ scale, unsigned short* __restrict__ C, int b)
{
    __shared__ __align__(16) unsigned short ash[32 * 512];   // 32 KB [i][hs][m]
    __shared__ __align__(16) unsigned short bsh[16 * 512];   // 16 KB [j][hs][m]
    const int tid = threadIdx.x;
    const int lane = tid & 63, w = tid >> 6;
    const int quad = lane >> 4, l15 = lane & 15;

    // bijective XCD swizzle: XCD k gets 64 contiguous tiles (grid 512 % 8 == 0)
    const int bid = blockIdx.x;
    const int swz = (bid & 7) * 64 + (bid >> 3);
    const int jt0 = (swz & 15) * 16;
    const int it0 = ((swz >> 4) & 7) * 32;
    const int hc  = swz >> 7;
    const int h0 = hc * 64;

    const int wit = (w >> 1) * 16;   // wave's i sub-tile base (0 or 16)
    const int hh0 = (w & 1) * 4;     // wave's hs half (0..3 or 4..7)
    const int ci = wit + quad * 4;   // lane's local i row base

    float scl[4];
#pragma unroll
    for (int r = 0; r < 4; ++r)
        scl[r] = scale[((size_t)(b * 256 + it0 + ci + r)) * 256 + jt0 + l15];

    const int hs_l = lane >> 3, mb_l = lane & 7;
    const int ai = wit + l15;
    const int sa0 = ai * 512 + ((quad ^ (ai & 7)) * 8);
    const int sa1 = ai * 512 + (((4 | quad) ^ (ai & 7)) * 8);
    const int sb0 = l15 * 512 + ((quad ^ (l15 & 7)) * 8);
    const int sb1 = l15 * 512 + (((4 | quad) ^ (l15 & 7)) * 8);

    uint2 pc[8][4];                  // packed bf16 C pieces (static indexing)

#pragma unroll
    for (int iter = 0; iter < 8; ++iter) {
        if (iter) __syncthreads();          // prev iter's LDS reads done
        const int hb = h0 + iter * 8;
        // stage: wave w loads 8 A-rows + 4 B-rows (1KB each, swizzled source)
#pragma unroll
        for (int k = 0; k < 8; ++k) {
            const int li = w * 8 + k;
            gload_lds16(
                Lt + ((size_t)(b * 256 + it0 + li) * 256 + hb + hs_l) * 64 +
                     ((mb_l ^ (li & 7)) * 8),
                &ash[li * 512]);
        }
#pragma unroll
        for (int k = 0; k < 4; ++k) {
            const int lj = w * 4 + k;
            gload_lds16(
                Rt + ((size_t)(b * 256 + jt0 + lj) * 256 + hb + hs_l) * 64 +
                     ((mb_l ^ (lj & 7)) * 8),
                &bsh[lj * 512]);
        }
        __syncthreads();                    // drains vmcnt (only loads now)

        f32x4 acch[4];
#pragma unroll
        for (int q = 0; q < 4; ++q) acch[q] = {0.f, 0.f, 0.f, 0.f};
#pragma unroll
        for (int q = 0; q < 4; ++q) {
            const int hs = hh0 + q;
            const bf16x8 a0 = *reinterpret_cast<const bf16x8*>(&ash[sa0 + hs * 64]);
            const bf16x8 a1 = *reinterpret_cast<const bf16x8*>(&ash[sa1 + hs * 64]);
            const bf16x8 b0 = *reinterpret_cast<const bf16x8*>(&bsh[sb0 + hs * 64]);
            const bf16x8 b1 = *reinterpret_cast<const bf16x8*>(&bsh[sb1 + hs * 64]);
            acch[q] = __builtin_amdgcn_mfma_f32_16x16x32_bf16(a0, b0, acch[q], 0, 0, 0);
            acch[q] = __builtin_amdgcn_mfma_f32_16x16x32_bf16(a1, b1, acch[q], 0, 0, 0);
        }
        // pack into registers (no global stores inside the loop)
#pragma unroll
        for (int r = 0; r < 4; ++r) {
            const float s = scl[r];
            uint2 p;
            p.x = f32_bf16(acch[0][r] * s) | (f32_bf16(acch[1][r] * s) << 16);
            p.y = f32_bf16(acch[2][r] * s) | (f32_bf16(acch[3][r] * s) << 16);
            pc[iter][r] = p;
        }
    }

    // single store phase; overlaps across blocks, L2 write-combines the lines
    unsigned short* Cbase = C + (size_t)hc * CPL +
        ((size_t)(it0 + ci) * 256 + jt0 + l15) * 64;
#pragma unroll
    for (int iter = 0; iter < 8; ++iter)
#pragma unroll
        for (int r = 0; r < 4; ++r)
            *reinterpret_cast<uint2*>(
                Cbase + (size_t)r * 16384 + iter * 8 + hh0) = pc[iter][r];
}

// ---------------------------------------------------------------------------
// K3: rows GEMM: out_row = bf16C_row @ bf16(Wo) + bo. A staged from the 4
// bf16 h-planes (plain uint4 copies, no conversion).
// ---------------------------------------------------------------------------
__global__ __launch_bounds__(256) void k_wo_mfma(
    float* __restrict__ io, const unsigned short* __restrict__ C,
    const unsigned short* __restrict__ Wp, const float* __restrict__ bo)
{
    __shared__ __align__(16) unsigned short ash[64 * 264];   // 33792 B
    __shared__ float4 bsh[1024];                             // 16384 B
    const int tid = threadIdx.x;
    const int lane = tid & 63, wave = tid >> 6;
    const int quad = lane >> 4, mrow = lane & 15;
    const size_t r0 = (size_t)blockIdx.x * 64;

    // Stage A: 64 rows x 256 bf16 from 4 planes (128B per plane per row).
#pragma unroll
    for (int it = 0; it < 8; ++it) {
        const int c = tid + it * 256;
        const int row = c >> 5, chunk = c & 31;
        *reinterpret_cast<uint4*>(&ash[row * 264 + chunk * 8]) =
            *reinterpret_cast<const uint4*>(
                C + (size_t)(chunk >> 3) * CPL + (r0 + row) * 64 + (chunk & 7) * 8);
    }

    f32x4 acc[16];
#pragma unroll
    for (int nt = 0; nt < 16; ++nt) acc[nt] = {0.f, 0.f, 0.f, 0.f};

    const float4* wpv = reinterpret_cast<const float4*>(Wp);
    const int arow = wave * 16 + mrow;

    for (int kb = 0; kb < 8; ++kb) {
        if (kb) __syncthreads();
#pragma unroll
        for (int it = 0; it < 4; ++it)
            bsh[tid + it * 256] = wpv[kb * 1024 + tid + it * 256];
        __syncthreads();

        const bf16x8 afr = *reinterpret_cast<const bf16x8*>(
            &ash[arow * 264 + kb * 32 + quad * 8]);
        const bf16x8* bptr = reinterpret_cast<const bf16x8*>(bsh);
#pragma unroll
        for (int nt = 0; nt < 16; ++nt) {
            bf16x8 bfr = bptr[nt * 64 + lane];
            acc[nt] = __builtin_amdgcn_mfma_f32_16x16x32_bf16(afr, bfr, acc[nt], 0, 0, 0);
        }
    }

#pragma unroll
    for (int nt = 0; nt < 16; ++nt) {
        const int col = nt * 16 + mrow;
        const float bov = bo[col];
#pragma unroll
        for (int r = 0; r < 4; ++r)
            io[(r0 + wave * 16 + quad * 4 + r) * 256 + col] = acc[nt][r] + bov;
    }
}

// ---------------------------------------------------------------------------
extern "C" void kernel_launch(void* const* d_in, const int* in_sizes, int n_in,
                              void* d_out, int out_size, void* d_ws, size_t ws_size,
                              hipStream_t stream)
{
    const float* x    = (const float*)d_in[0];
    const int*   mask = (const int*)  d_in[1];
    const float* ln_w = (const float*)d_in[2];
    const float* ln_b = (const float*)d_in[3];
    const float* Wl   = (const float*)d_in[4];
    const float* bl   = (const float*)d_in[5];
    const float* Wr   = (const float*)d_in[6];
    const float* br   = (const float*)d_in[7];
    const float* Wo   = (const float*)d_in[8];
    const float* bo   = (const float*)d_in[9];

    float* out = (float*)d_out;
    char*  ws  = (char*)d_ws;
    unsigned short* Lt    = (unsigned short*)(ws);                 // 16 MiB [b][i][h][m]
    unsigned short* Rt    = (unsigned short*)(ws + 16777216);      // 16 MiB [b][j][h][m]
    float*          scale = (float*)         (ws + 33554432);      // 512 KiB
    unsigned short* Wp    = (unsigned short*)(ws + 34078720);      // 128 KiB (Wo)
    unsigned short* Wp2   = (unsigned short*)(ws + 34209792);      // 256 KiB (Wl|Wr)
    unsigned short* C     = (unsigned short*)(ws + 34471936);      // 32 MiB, reused per b

    k_setup<<<608, 256, 0, stream>>>(Wl, Wr, Wo, mask, Wp2, Wp, scale);
    k_projln<<<512, 256, 0, stream>>>(x, mask, Wp2, ln_w, ln_b, bl, br, Lt, Rt);
    for (int b = 0; b < 2; ++b) {
        k_outer_mfma<<<512, 256, 0, stream>>>(Lt, Rt, scale, C, b);
        k_wo_mfma<<<1024, 256, 0, stream>>>(out + (size_t)b * 65536 * 256, C, Wp, bo);
    }
}